// Round 8
// baseline (51.419 us; speedup 1.0000x reference)
//
#include <hip/hip_runtime.h>
#include <hip/hip_bf16.h>
#include <stdint.h>

// Problem constants
#define D       256
#define KCB     1024
#define HW      1024        // 32*32
#define NROWS   32768       // 32*32*32
#define TOTAL   8388608     // 32*256*32*32
#define BM      64          // z-rows per WG
#define BN      32          // codes per tile
#define NTILES  32

// ws layout (bytes)
#define WS_EMBBF 0          // 1024*256*2 = 524288, pre-swizzled bf16, 32 tiles x 16KB
#define WS_CINIT 524288     // 1024*4  : 1 - 0.5*|e|^2 per code

typedef __bf16 bf16x8 __attribute__((ext_vector_type(8)));
typedef float  f32x4  __attribute__((ext_vector_type(4)));
typedef unsigned int u32x4 __attribute__((ext_vector_type(4)));
typedef unsigned int u32x2 __attribute__((ext_vector_type(2)));

union Pack8 { __bf16 h[8]; u32x4 u; };
union Pack4 { __bf16 h[4]; u32x2 u; };
union FU    { float f; unsigned u; };

__device__ __forceinline__ void gload_lds16(const void* g, void* l) {
  __builtin_amdgcn_global_load_lds(
      (__attribute__((address_space(1))) void*)(uintptr_t)g,
      (__attribute__((address_space(3))) void*)l, 16, 0, 0);
}

// ---------------- K1: c_init (1 - 0.5|e|^2) + bf16 emb, pre-swizzled --------
// One wave per codebook row; 32-code tiles (16KB each). Byte-col c of row rl
// stored at c ^ ((rl&7)<<4). Also zeroes the loss slot.
__global__ __launch_bounds__(256) void k_prep(const float* __restrict__ emb,
                                              unsigned char* __restrict__ ws,
                                              float* __restrict__ loss_slot) {
  const int t = threadIdx.x;
  if (blockIdx.x == 0 && t == 0) *loss_slot = 0.0f;
  const int wave = (blockIdx.x * 256 + t) >> 6;  // 0..1023 = emb row
  const int lane = t & 63;
  const float4 v = *reinterpret_cast<const float4*>(emb + wave * D + lane * 4);
  float ss = v.x * v.x + v.y * v.y + v.z * v.z + v.w * v.w;
  #pragma unroll
  for (int m = 1; m < 64; m <<= 1) ss += __shfl_xor(ss, m, 64);
  if (lane == 0)
    *reinterpret_cast<float*>(ws + WS_CINIT + wave * 4) = 1.0f - 0.5f * ss;

  Pack4 p;
  p.h[0] = (__bf16)v.x; p.h[1] = (__bf16)v.y; p.h[2] = (__bf16)v.z; p.h[3] = (__bf16)v.w;
  const int tile = wave >> 5, rl = wave & 31;
  const unsigned u = (unsigned)(lane * 8) ^ (unsigned)((rl & 7) << 4);
  *reinterpret_cast<u32x2*>(ws + WS_EMBBF + tile * 16384 + rl * 512 + u) = p.u;
}

// ---------------- K2: fused dist + argmin + loss + gather + output ----------
// 512 WGs x 256 threads (4 waves), 2 WG/CU (LDS 67KB) -> cross-WG phase overlap.
// WG = 64 z-rows vs 1024 codes in 32 tiles of 32. acc = 1 + z.e - .5|e|^2
// (positive -> IEEE bits monotone); argmin = argmax(key), key =
// (bits&~1023)|(1023-col). Loss: sum_d (q-z)^2 = |z|^2 - 2(acc_w - 1).
// Then coalesced gather of 64 winner rows into swizzled LDS + transposed write.
__global__ __launch_bounds__(256, 2) void k_fused(const float* __restrict__ z,
                                                  const unsigned char* __restrict__ embbf,
                                                  const float* __restrict__ c_init,
                                                  const float* __restrict__ embf32,
                                                  float* __restrict__ out,
                                                  float* __restrict__ loss_slot) {
  __shared__ unsigned char smem[65536];  // [0,32K)=z_lds [32K,48K)=ebuf0 [48K,64K)=ebuf1/scratch
  __shared__ float zsq_buf[4][64];       // per-row |z|^2 quarters
  __shared__ int   idx_l[64];            // per-row winner index

  unsigned char* z_lds = smem;           // named bases only (addrspace-init bug)

  const int t    = threadIdx.x;
  const int lane = t & 63;
  const int w    = t >> 6;        // 0..3
  const int wm   = w >> 1;        // 0..1 : 32-row block
  const int wn   = w & 1;         // 0..1 : 16-col block within 32-code tile
  const int crl  = lane & 15;
  const int g    = lane >> 4;     // 0..3
  const int row0 = blockIdx.x * BM;
  const int b    = row0 >> 10;
  const int hw0  = row0 & 1023;
  const float* zb = z + (size_t)b * (D * HW) + hw0;

  // Prefetch code tile 0 into ebuf0 (async, overlaps z staging)
  #pragma unroll
  for (int i = 0; i < 4; ++i)
    gload_lds16(embbf + w * 4096 + i * 1024 + lane * 16,
                smem + 32768 + w * 4096 + i * 1024);

  // ---- Stage z: float4 global -> f32 scratch (64d x 64hw) -> bf16 swz LDS
  float* scratch = reinterpret_cast<float*>(smem + 49152);
  const int row = t & 63;
  const int kc  = t >> 6;                  // 0..3
  float zsq_part = 0.f;
  for (int c = 0; c < 4; ++c) {
    #pragma unroll
    for (int i = 0; i < 4; ++i) {
      const int s   = t + i * 256;         // 0..1023
      const int dl  = s >> 4;              // 0..63
      const int hw4 = s & 15;              // 0..15
      *reinterpret_cast<float4*>(scratch + dl * 64 + hw4 * 4) =
          *reinterpret_cast<const float4*>(zb + (size_t)(c * 64 + dl) * HW + hw4 * 4);
    }
    __syncthreads();
    #pragma unroll
    for (int kk = 0; kk < 2; ++kk) {
      const int kcI = kc + kk * 4;         // 0..7 (8 d each)
      Pack8 p;
      #pragma unroll
      for (int q = 0; q < 8; ++q) {
        const float f = scratch[(kcI * 8 + q) * 64 + row];
        zsq_part += f * f;
        p.h[q] = (__bf16)f;
      }
      const unsigned u = (unsigned)(c * 128 + kcI * 16) ^ (unsigned)((row & 7) << 4);
      *reinterpret_cast<u32x4*>(&z_lds[row * 512 + u]) = p.u;
    }
    __syncthreads();
  }
  zsq_buf[kc][row] = zsq_part;

  // ---- Hoist A-fragments: 32 rows x full K per wave (64 VGPR, stationary)
  bf16x8 afrag[2][8];
  #pragma unroll
  for (int m = 0; m < 2; ++m) {
    const int rl = wm * 32 + m * 16 + crl;
    const unsigned s = (unsigned)((rl & 7) << 4);
    #pragma unroll
    for (int kb = 0; kb < 8; ++kb) {
      const unsigned db = (unsigned)(kb * 64 + g * 16) ^ s;
      afrag[m][kb] = *reinterpret_cast<const bf16x8*>(&z_lds[rl * 512 + db]);
    }
  }
  __syncthreads();   // tile 0 staged (vmcnt drained) & visible

  unsigned kmax[2][4];
  #pragma unroll
  for (int m = 0; m < 2; ++m)
    #pragma unroll
    for (int r = 0; r < 4; ++r) kmax[m][r] = 0u;

  const int er = wn * 16 + crl;                 // B row within 32-code tile
  const unsigned esw = (unsigned)((er & 7) << 4);
  float ci = c_init[er];                        // tile 0 cols
  int cur = 0;

  for (int tile = 0; tile < NTILES; ++tile) {
    // 2-phase: issue next tile's staging BEFORE compute
    if (tile < NTILES - 1) {
      const unsigned char* src = embbf + (tile + 1) * 16384 + w * 4096 + lane * 16;
      unsigned char* dst = smem + 32768 + ((cur ^ 1) << 14) + w * 4096;
      #pragma unroll
      for (int i = 0; i < 4; ++i) gload_lds16(src + i * 1024, dst + i * 1024);
    }
    const float ci_next = (tile < NTILES - 1) ? c_init[(tile + 1) * BN + er] : 0.f;

    f32x4 acc[2];
    #pragma unroll
    for (int m = 0; m < 2; ++m) { acc[m][0] = ci; acc[m][1] = ci; acc[m][2] = ci; acc[m][3] = ci; }

    const unsigned char* ecur = smem + 32768 + (cur << 14);
    #pragma unroll
    for (int kb = 0; kb < 8; ++kb) {
      const unsigned db = (unsigned)(kb * 64 + g * 16) ^ esw;
      const bf16x8 bfr = *reinterpret_cast<const bf16x8*>(&ecur[er * 512 + db]);
      acc[0] = __builtin_amdgcn_mfma_f32_16x16x32_bf16(afrag[0][kb], bfr, acc[0], 0, 0, 0);
      acc[1] = __builtin_amdgcn_mfma_f32_16x16x32_bf16(afrag[1][kb], bfr, acc[1], 0, 0, 0);
    }

    // epilogue: 2 VALU ops per element (and_or + max)
    const unsigned colcode = (unsigned)(1023 - (tile * BN + er));
    #pragma unroll
    for (int m = 0; m < 2; ++m)
      #pragma unroll
      for (int r = 0; r < 4; ++r) {
        FU fu; fu.f = acc[m][r];
        const unsigned key = (fu.u & 0xFFFFFC00u) | colcode;
        kmax[m][r] = kmax[m][r] > key ? kmax[m][r] : key;
      }

    ci = ci_next;
    __syncthreads();                            // drains vmcnt: next tile ready
    cur ^= 1;
  }

  // ---- reduce over the 16 col-lanes of each row-group
  #pragma unroll
  for (int s = 1; s <= 8; s <<= 1)
    #pragma unroll
    for (int m = 0; m < 2; ++m)
      #pragma unroll
      for (int r = 0; r < 4; ++r) {
        const unsigned o = __shfl_xor(kmax[m][r], s, 64);
        kmax[m][r] = kmax[m][r] > o ? kmax[m][r] : o;
      }

  // combine the 2 wn-waves' partial argmax per row (kbuf in dead ebuf0)
  unsigned* kbuf = reinterpret_cast<unsigned*>(smem + 32768);   // 64 x 2 u32
  if (crl == 0) {
    #pragma unroll
    for (int m = 0; m < 2; ++m)
      #pragma unroll
      for (int r = 0; r < 4; ++r)
        kbuf[(wm * 32 + m * 16 + g * 4 + r) * 2 + wn] = kmax[m][r];
  }
  __syncthreads();

  if (t < 64) {
    const unsigned k0 = kbuf[t * 2 + 0], k1 = kbuf[t * 2 + 1];
    const unsigned km = k0 > k1 ? k0 : k1;
    idx_l[t] = 1023 - (int)(km & 1023u);
    FU fu; fu.u = km & 0xFFFFFC00u;             // winner acc (trunc, +ve -> valid)
    const float zsq = zsq_buf[0][t] + zsq_buf[1][t] + zsq_buf[2][t] + zsq_buf[3][t];
    float myloss = zsq - 2.0f * (fu.f - 1.0f);  // sum_d (q - z)^2 for this row
    #pragma unroll
    for (int m = 1; m < 64; m <<= 1) myloss += __shfl_xor(myloss, m, 64);
    if (t == 0)
      atomicAdd(loss_slot, myloss * (1.25f / 8388608.0f));
  }
  __syncthreads();   // idx_l visible; kbuf read done -> smem reusable as gb

  // ---- Gather: 64 winner emb rows, coalesced (1KB/row), swizzled LDS
  const float4* emb4 = reinterpret_cast<const float4*>(embf32);
  #pragma unroll
  for (int i = 0; i < 16; ++i) {
    const int r = w * 16 + i;
    const int k = idx_l[r];
    const float4 v = emb4[(size_t)k * 64 + lane];
    *reinterpret_cast<float4*>(
        &smem[r * 1024 + ((unsigned)(lane * 16) ^ (unsigned)((r & 7) << 4))]) = v;
  }
  __syncthreads();

  // ---- Transposed write-out: lane = hw row, wave covers 64 d (16 dq);
  // b128 LDS read (4 d) -> 4 coalesced scalar stores (256B/instr over hw).
  {
    const int r = lane;
    const unsigned rsw = (unsigned)((r & 7) << 4);
    float* outb = out + (size_t)b * (D * HW) + (size_t)(hw0 + r);
    #pragma unroll
    for (int i = 0; i < 16; ++i) {
      const int dq = w * 16 + i;
      const f32x4 v = *reinterpret_cast<const f32x4*>(
          &smem[r * 1024 + ((unsigned)(dq * 16) ^ rsw)]);
      #pragma unroll
      for (int q = 0; q < 4; ++q)
        outb[(size_t)(dq * 4 + q) * HW] = v[q];
    }
  }
}

extern "C" void kernel_launch(void* const* d_in, const int* in_sizes, int n_in,
                              void* d_out, int out_size, void* d_ws, size_t ws_size,
                              hipStream_t stream) {
  (void)in_sizes; (void)n_in; (void)out_size; (void)ws_size;
  const float* z   = (const float*)d_in[0];
  const float* emb = (const float*)d_in[1];
  float* out = (float*)d_out;
  unsigned char* ws = (unsigned char*)d_ws;

  k_prep<<<256, 256, 0, stream>>>(emb, ws, out + TOTAL);
  k_fused<<<512, 256, 0, stream>>>(z, ws + WS_EMBBF,
                                   (const float*)(ws + WS_CINIT),
                                   emb, out, out + TOTAL);
}